// Round 1
// baseline (124.589 us; speedup 1.0000x reference)
//
#include <hip/hip_runtime.h>

#define BATCH 4
#define CH    128
#define HW    128
#define PAD   10
#define PW    148        // 128 + 2*10
#define WIN   21
#define NUV   441

typedef short s16x8 __attribute__((ext_vector_type(8)));
typedef float f32x4 __attribute__((ext_vector_type(4)));

static __device__ __forceinline__ unsigned short f32_to_bf16(float f) {
    unsigned int u = __float_as_uint(f);
    u += 0x7FFFu + ((u >> 16) & 1u);       // RNE
    return (unsigned short)(u >> 16);
}

// -------- transpose+convert: x[b][c][i][j] f32 -> channels-last bf16 --------
// blocks [0,8192): x1 -> x1b [4][128][128][128]
// blocks [8192,16384): x2 -> x2b [4][148][148][128] at +PAD offsets (borders pre-zeroed)
__global__ __launch_bounds__(256) void corr_transpose_kernel(
    const float* __restrict__ x1, const float* __restrict__ x2,
    unsigned short* __restrict__ x1b, unsigned short* __restrict__ x2b)
{
    __shared__ float lds[32][33];
    int bidx = blockIdx.x;
    int which = (bidx >= 8192) ? 1 : 0;
    if (which) bidx -= 8192;
    int tjt = bidx & 3;
    int tct = (bidx >> 2) & 3;
    int i   = (bidx >> 4) & 127;
    int b   = bidx >> 11;
    int c0 = tct * 32, j0 = tjt * 32;
    int t  = threadIdx.x;
    int tx = t & 31, ty = t >> 5;

    const float* __restrict__ src = which ? x2 : x1;
    #pragma unroll
    for (int k = 0; k < 4; ++k) {
        int c = c0 + ty + k * 8;
        lds[ty + k * 8][tx] = src[(((size_t)b * CH + c) * HW + i) * HW + j0 + tx];
    }
    __syncthreads();
    if (!which) {
        #pragma unroll
        for (int k = 0; k < 4; ++k) {
            int j = j0 + ty + k * 8;
            x1b[(((size_t)b * HW + i) * HW + j) * CH + c0 + tx] = f32_to_bf16(lds[tx][ty + k * 8]);
        }
    } else {
        #pragma unroll
        for (int k = 0; k < 4; ++k) {
            int j = j0 + ty + k * 8;
            x2b[(((size_t)b * PW + i + PAD) * PW + (j + PAD)) * CH + c0 + tx] = f32_to_bf16(lds[tx][ty + k * 8]);
        }
    }
}

// -------- correlation GEMM --------
// grid: 1024 blocks = 4 b x 16 ti x 16 tj (XCD-swizzled). block: 512 thr = 8 waves.
// Per block: M=64 (8x8 x1 pixels), N=784 (28x28 x2 region), K=128 channels.
// Wave w owns N-tiles {w, w+8, ...} (7 slots, clamped to tile 48 -> dup compute, never written).
__global__ __launch_bounds__(512, 2) void corr_mfma_kernel(
    const unsigned short* __restrict__ x1b,
    const unsigned short* __restrict__ x2b,
    float* __restrict__ out)
{
    __shared__ unsigned short ldsA[64 * 128];   // 16 KB, chunk-swizzled
    __shared__ float ldsC[64 * 113];            // C restage, pad 112->113

    int bid = blockIdx.x;
    int swz = (bid & 7) * 128 + (bid >> 3);     // XCD-contiguous chunks
    int b   = swz >> 8;
    int ti  = (swz >> 4) & 15;
    int tj  = swz & 15;
    int i0 = ti * 8, j0 = tj * 8;

    int t    = threadIdx.x;
    int lane = t & 63;
    int w    = t >> 6;            // wave 0..7
    int l15  = lane & 15;
    int lhi  = lane >> 4;         // 0..3

    // ---- stage A tile (64 pixels x 128 ch bf16) into LDS, chunk-XOR swizzle ----
    #pragma unroll
    for (int it = 0; it < 2; ++it) {
        int s  = it * 512 + t;        // 0..1023 16B-chunks
        int p  = s >> 4;              // pixel 0..63
        int hs = s & 15;              // stored slot
        int h  = hs ^ (p & 7);        // source chunk (pre-swizzled global src)
        int dpi = p >> 3, dpj = p & 7;
        const s16x8* g = (const s16x8*)(x1b + ((((size_t)b * HW + i0 + dpi) * HW + j0 + dpj) * CH + h * 8));
        *(s16x8*)(ldsA + p * 128 + hs * 8) = *g;
    }
    __syncthreads();

    // ---- per-lane base pointers for owned B tiles ----
    const unsigned short* bp[7];
    #pragma unroll
    for (int kk = 0; kk < 7; ++kk) {
        int nt = w + 8 * kk; if (nt > 48) nt = 48;     // clamp (dup compute, never stored)
        int q   = nt * 16 + l15;
        int dqi = q / 28;
        int dqj = q - dqi * 28;
        bp[kk] = x2b + (((size_t)b * PW + i0 + dqi) * PW + j0 + dqj) * CH + lhi * 8;
    }

    f32x4 acc[7][4];
    #pragma unroll
    for (int kk = 0; kk < 7; ++kk)
        #pragma unroll
        for (int mt = 0; mt < 4; ++mt)
            acc[kk][mt] = (f32x4)(0.0f);

    s16x8 bcur[7], bnxt[7];
    #pragma unroll
    for (int kk = 0; kk < 7; ++kk) bcur[kk] = *(const s16x8*)(bp[kk]);

    #pragma unroll
    for (int kc = 0; kc < 4; ++kc) {
        if (kc < 3) {
            #pragma unroll
            for (int kk = 0; kk < 7; ++kk) bnxt[kk] = *(const s16x8*)(bp[kk] + (kc + 1) * 32);
        }
        s16x8 a[4];
        #pragma unroll
        for (int mt = 0; mt < 4; ++mt) {
            int p  = mt * 16 + l15;
            int hs = (kc * 4 + lhi) ^ (p & 7);
            a[mt] = *(const s16x8*)(ldsA + p * 128 + hs * 8);
        }
        #pragma unroll
        for (int kk = 0; kk < 7; ++kk)
            #pragma unroll
            for (int mt = 0; mt < 4; ++mt)
                acc[kk][mt] = __builtin_amdgcn_mfma_f32_16x16x32_bf16(a[mt], bcur[kk], acc[kk][mt], 0, 0, 0);
        #pragma unroll
        for (int kk = 0; kk < 7; ++kk) bcur[kk] = bnxt[kk];
    }

    // ---- epilogue: 7 chunks of 4 region-rows (112 q = 7 N-tiles) each ----
    int dpj = t & 7;
    #pragma unroll 1
    for (int r = 0; r < 7; ++r) {
        __syncthreads();   // prev chunk's reads done before overwrite
        // each wave writes its (at most one) tile in tiles [7r, 7r+7)
        #pragma unroll
        for (int kk = 0; kk < 7; ++kk) {
            int nt = w + 8 * kk;
            if (nt >= 7 * r && nt < 7 * r + 7 && nt <= 48) {
                int qloc = (nt - 7 * r) * 16 + l15;
                #pragma unroll
                for (int mt = 0; mt < 4; ++mt) {
                    #pragma unroll
                    for (int reg = 0; reg < 4; ++reg) {
                        ldsC[(mt * 16 + lhi * 4 + reg) * 113 + qloc] = acc[kk][mt][reg];
                    }
                }
            }
        }
        __syncthreads();
        // rows: 32 combos (dpi 0..7 x du 0..3) x 21 v; 8 lanes (dpj) per row
        #pragma unroll 1
        for (int rowid = (t >> 3); rowid < 672; rowid += 64) {
            int combo = rowid / 21;
            int v     = rowid - combo * 21;
            int dpi   = combo >> 2;
            int du    = combo & 3;
            int u     = 4 * r + du - dpi;
            if ((unsigned)u < 21u) {
                float val = ldsC[(dpi * 8 + dpj) * 113 + du * 28 + dpj + v];
                out[(((size_t)b * NUV + u * 21 + v) * HW + i0 + dpi) * HW + j0 + dpj] = val;
            }
        }
    }
}

extern "C" void kernel_launch(void* const* d_in, const int* in_sizes, int n_in,
                              void* d_out, int out_size, void* d_ws, size_t ws_size,
                              hipStream_t stream) {
    const float* x1 = (const float*)d_in[0];
    const float* x2 = (const float*)d_in[1];
    float* out = (float*)d_out;

    const size_t X1B_ELEMS = (size_t)BATCH * HW * HW * CH;          // 8,388,608
    const size_t X2B_ELEMS = (size_t)BATCH * PW * PW * CH;          // 11,214,848
    if (ws_size < (X1B_ELEMS + X2B_ELEMS) * sizeof(unsigned short)) return;

    unsigned short* x1b = (unsigned short*)d_ws;
    unsigned short* x2b = x1b + X1B_ELEMS;

    hipMemsetAsync(x2b, 0, X2B_ELEMS * sizeof(unsigned short), stream);
    corr_transpose_kernel<<<16384, 256, 0, stream>>>(x1, x2, x1b, x2b);
    corr_mfma_kernel<<<1024, 512, 0, stream>>>(x1b, x2b, out);
}

// Round 2
// 117.818 us; speedup vs baseline: 1.0575x; 1.0575x over previous
//
#include <hip/hip_runtime.h>

#define BATCH 4
#define CH    128
#define HW    128
#define PAD   10
#define PW    148        // x2b rows (128 + 2*10)
#define PWC   160        // x2b row stride in cols (padded so j0+qc<=159 stays in-bounds, zeros)
#define WIN   21
#define NUV   441

typedef short s16x8 __attribute__((ext_vector_type(8)));
typedef float f32x4 __attribute__((ext_vector_type(4)));

static __device__ __forceinline__ unsigned short f32_to_bf16(float f) {
    unsigned int u = __float_as_uint(f);
    u += 0x7FFFu + ((u >> 16) & 1u);       // RNE
    return (unsigned short)(u >> 16);
}

// -------- transpose+convert: x[b][c][i][j] f32 -> channels-last bf16 --------
// blocks [0,8192): x1 -> x1b [4][128][128][128]
// blocks [8192,16384): x2 -> x2b [4][148][160][128] at +PAD offsets (borders pre-zeroed)
__global__ __launch_bounds__(256) void corr_transpose_kernel(
    const float* __restrict__ x1, const float* __restrict__ x2,
    unsigned short* __restrict__ x1b, unsigned short* __restrict__ x2b)
{
    __shared__ float lds[32][33];
    int bidx = blockIdx.x;
    int which = (bidx >= 8192) ? 1 : 0;
    if (which) bidx -= 8192;
    int tjt = bidx & 3;
    int tct = (bidx >> 2) & 3;
    int i   = (bidx >> 4) & 127;
    int b   = bidx >> 11;
    int c0 = tct * 32, j0 = tjt * 32;
    int t  = threadIdx.x;
    int tx = t & 31, ty = t >> 5;

    const float* __restrict__ src = which ? x2 : x1;
    #pragma unroll
    for (int k = 0; k < 4; ++k) {
        int c = c0 + ty + k * 8;
        lds[ty + k * 8][tx] = src[(((size_t)b * CH + c) * HW + i) * HW + j0 + tx];
    }
    __syncthreads();
    if (!which) {
        #pragma unroll
        for (int k = 0; k < 4; ++k) {
            int j = j0 + ty + k * 8;
            x1b[(((size_t)b * HW + i) * HW + j) * CH + c0 + tx] = f32_to_bf16(lds[tx][ty + k * 8]);
        }
    } else {
        #pragma unroll
        for (int k = 0; k < 4; ++k) {
            int j = j0 + ty + k * 8;
            x2b[(((size_t)b * PW + i + PAD) * PWC + (j + PAD)) * CH + c0 + tx] = f32_to_bf16(lds[tx][ty + k * 8]);
        }
    }
}

// -------- correlation GEMM, barrier-free --------
// grid: 3072 = 4 b x 32 ti x 8 tj x 3 z (XCD-swizzled). block: 512 thr = 8 waves.
// Pixel tile: 4x16 (M=64, mt == dpi). Region rows 24 (rr = z*8 + wave), row = 48 q = 3 N-tiles.
// Each wave owns ONE region row: acc[3 nt][4 mt], fully wave-private epilogue (no barriers).
__global__ __launch_bounds__(512, 4) void corr_mfma_kernel(
    const unsigned short* __restrict__ x1b,
    const unsigned short* __restrict__ x2b,
    float* __restrict__ out)
{
    __shared__ float ldsC[8][16][49];   // per-wave C restage, 25 KB

    int bid  = blockIdx.x;
    int swz  = (bid & 7) * 384 + (bid >> 3);   // XCD-contiguous chunks
    int z    = swz % 3;
    int rest = swz / 3;                        // 0..1023
    int tj   = rest & 7;
    int ti   = (rest >> 3) & 31;
    int b    = rest >> 8;
    int i0 = ti * 4, j0 = tj * 16;

    int t    = threadIdx.x;
    int lane = t & 63;
    int w    = t >> 6;
    int l15  = lane & 15;
    int lhi  = lane >> 4;          // 0..3
    int rr   = z * 8 + w;          // owned region row, 0..23

    // A fragments: direct global (dense at cache-line level, identical across waves -> L2 hits)
    const unsigned short* ap  = x1b + (((size_t)(b * HW + i0) * HW) + j0 + l15) * CH + lhi * 8;
    // B fragments: region row rr, cols j0 + ntl*16 + l15
    const unsigned short* bpb = x2b + (((size_t)(b * PW + i0 + rr) * PWC) + j0 + l15) * CH + lhi * 8;

    f32x4 acc[3][4];
    #pragma unroll
    for (int ntl = 0; ntl < 3; ++ntl)
        #pragma unroll
        for (int mt = 0; mt < 4; ++mt)
            acc[ntl][mt] = (f32x4)(0.0f);

    #pragma unroll
    for (int kc = 0; kc < 4; ++kc) {
        s16x8 bb[3], a[4];
        #pragma unroll
        for (int ntl = 0; ntl < 3; ++ntl)
            bb[ntl] = *(const s16x8*)(bpb + (size_t)ntl * (16 * CH) + kc * 32);
        #pragma unroll
        for (int mt = 0; mt < 4; ++mt)
            a[mt] = *(const s16x8*)(ap + (size_t)mt * (HW * CH) + kc * 32);
        #pragma unroll
        for (int ntl = 0; ntl < 3; ++ntl)
            #pragma unroll
            for (int mt = 0; mt < 4; ++mt)
                acc[ntl][mt] = __builtin_amdgcn_mfma_f32_16x16x32_bf16(a[mt], bb[ntl], acc[ntl][mt], 0, 0, 0);
    }

    // ---- wave-private epilogue: for each dpi with u = rr-dpi in range, restage + store ----
    float (*myC)[49] = ldsC[w];
    #pragma unroll
    for (int dpi = 0; dpi < 4; ++dpi) {
        int u = rr - dpi;                       // wave-uniform
        if ((unsigned)u < 21u) {
            // dump mt=dpi slice: value(pixel dpj = lhi*4+reg, qc = ntl*16 + l15)
            #pragma unroll
            for (int ntl = 0; ntl < 3; ++ntl)
                #pragma unroll
                for (int reg = 0; reg < 4; ++reg)
                    myC[lhi * 4 + reg][ntl * 16 + l15] = acc[ntl][dpi][reg];
            // read diagonal (dpj = l15, qc = l15 + v), store 16-contiguous j rows
            #pragma unroll
            for (int vb = 0; vb < 6; ++vb) {
                int v = vb * 4 + lhi;
                if (v < 21) {
                    float val = myC[l15][l15 + v];
                    out[(((size_t)b * NUV + u * WIN + v) * HW + (i0 + dpi)) * HW + j0 + l15] = val;
                }
            }
        }
    }
}

extern "C" void kernel_launch(void* const* d_in, const int* in_sizes, int n_in,
                              void* d_out, int out_size, void* d_ws, size_t ws_size,
                              hipStream_t stream) {
    const float* x1 = (const float*)d_in[0];
    const float* x2 = (const float*)d_in[1];
    float* out = (float*)d_out;

    const size_t X1B_ELEMS = (size_t)BATCH * HW * HW * CH;          // 8,388,608
    const size_t X2B_ELEMS = (size_t)BATCH * PW * PWC * CH;         // 12,124,160
    if (ws_size < (X1B_ELEMS + X2B_ELEMS) * sizeof(unsigned short)) return;

    unsigned short* x1b = (unsigned short*)d_ws;
    unsigned short* x2b = x1b + X1B_ELEMS;

    hipMemsetAsync(x2b, 0, X2B_ELEMS * sizeof(unsigned short), stream);
    corr_transpose_kernel<<<16384, 256, 0, stream>>>(x1, x2, x1b, x2b);
    corr_mfma_kernel<<<3072, 512, 0, stream>>>(x1b, x2b, out);
}

// Round 3
// 80.496 us; speedup vs baseline: 1.5478x; 1.4636x over previous
//
#include <hip/hip_runtime.h>

#define BATCH 4
#define CH    128
#define HW    128
#define PAD   10
#define PW    148        // x2b rows (128 + 2*10)
#define PWC   160        // x2b row stride in cols (padded so j0+qc<=159 stays in-bounds, zeros)
#define WIN   21
#define NUV   441

typedef short s16x8 __attribute__((ext_vector_type(8)));
typedef float f32x4 __attribute__((ext_vector_type(4)));

static __device__ __forceinline__ unsigned short f32_to_bf16(float f) {
    unsigned int u = __float_as_uint(f);
    u += 0x7FFFu + ((u >> 16) & 1u);       // RNE
    return (unsigned short)(u >> 16);
}

// -------- transpose+convert: x[b][c][i][j] f32 -> channels-last bf16 --------
__global__ __launch_bounds__(256) void corr_transpose_kernel(
    const float* __restrict__ x1, const float* __restrict__ x2,
    unsigned short* __restrict__ x1b, unsigned short* __restrict__ x2b)
{
    __shared__ float lds[32][33];
    int bidx = blockIdx.x;
    int which = (bidx >= 8192) ? 1 : 0;
    if (which) bidx -= 8192;
    int tjt = bidx & 3;
    int tct = (bidx >> 2) & 3;
    int i   = (bidx >> 4) & 127;
    int b   = bidx >> 11;
    int c0 = tct * 32, j0 = tjt * 32;
    int t  = threadIdx.x;
    int tx = t & 31, ty = t >> 5;

    const float* __restrict__ src = which ? x2 : x1;
    #pragma unroll
    for (int k = 0; k < 4; ++k) {
        int c = c0 + ty + k * 8;
        lds[ty + k * 8][tx] = src[(((size_t)b * CH + c) * HW + i) * HW + j0 + tx];
    }
    __syncthreads();
    if (!which) {
        #pragma unroll
        for (int k = 0; k < 4; ++k) {
            int j = j0 + ty + k * 8;
            x1b[(((size_t)b * HW + i) * HW + j) * CH + c0 + tx] = f32_to_bf16(lds[tx][ty + k * 8]);
        }
    } else {
        #pragma unroll
        for (int k = 0; k < 4; ++k) {
            int j = j0 + ty + k * 8;
            x2b[(((size_t)b * PW + i + PAD) * PWC + (j + PAD)) * CH + c0 + tx] = f32_to_bf16(lds[tx][ty + k * 8]);
        }
    }
}

// -------- correlation GEMM, barrier-light --------
// grid: 3072 = 4 b x 32 ti x 8 tj x 3 z (XCD-swizzled). block: 512 thr = 8 waves.
// Pixel tile: 4x16 (M=64, mt == dpi). Each wave owns region row rr = z*8+w (48 q = 3 N-tiles).
// A tile staged once in LDS (global_load_lds, XOR-chunk swizzle); B direct global w/ prefetch.
// Epilogue: per-wave transposed C slice in LDS (b128 writes), diagonal read, coalesced stores.
__global__ __launch_bounds__(512, 4) void corr_mfma_kernel(
    const unsigned short* __restrict__ x1b,
    const unsigned short* __restrict__ x2b,
    float* __restrict__ out)
{
    __shared__ unsigned short ldsA[64 * 128];   // [pixel p][chunk-slot hs]*8shorts, 16 KB
    __shared__ float ldsCT[8][48][20];          // per-wave C slice, transposed [qc][dpj], 30 KB

    int bid  = blockIdx.x;
    int swz  = (bid & 7) * 384 + (bid >> 3);   // XCD-contiguous chunks
    int z    = swz % 3;
    int rest = swz / 3;                        // 0..1023
    int tj   = rest & 7;
    int ti   = (rest >> 3) & 31;
    int b    = rest >> 8;
    int i0 = ti * 4, j0 = tj * 16;

    int t    = threadIdx.x;
    int lane = t & 63;
    int w    = t >> 6;
    int l15  = lane & 15;
    int lhi  = lane >> 4;          // 0..3
    int rr   = z * 8 + w;          // owned region row, 0..23

    // ---- stage A tile: 64 px x 128 ch bf16 = 16 KB, 2 global_load_lds per wave ----
    #pragma unroll
    for (int it = 0; it < 2; ++it) {
        int s   = it * 8 + w;          // 0..15, 1 KB each
        int dpi = s >> 2;
        int k   = lane >> 4;           // 0..3
        int hs  = lane & 15;           // dest chunk slot
        int p   = s * 4 + k;
        int dpj = (s & 3) * 4 + k;
        int h   = hs ^ (p & 7);        // source chunk (pre-swizzled global src, linear LDS dest)
        const unsigned short* src =
            x1b + (((size_t)b * HW + i0 + dpi) * HW + j0 + dpj) * CH + h * 8;
        __builtin_amdgcn_global_load_lds(
            (const __attribute__((address_space(1))) void*)src,
            (__attribute__((address_space(3))) void*)(ldsA + s * 4 * 128),
            16, 0, 0);
    }

    // ---- B pointers + first-kc loads issued before the barrier (latency hides under it) ----
    const unsigned short* bpb =
        x2b + (((size_t)b * PW + i0 + rr) * PWC + j0 + l15) * CH + lhi * 8;

    s16x8 bcur[3], bnxt[3];
    #pragma unroll
    for (int ntl = 0; ntl < 3; ++ntl)
        bcur[ntl] = *(const s16x8*)(bpb + (size_t)ntl * (16 * CH));

    __syncthreads();   // A staged (vmcnt(0) drain covers global_load_lds)

    f32x4 acc[3][4];
    #pragma unroll
    for (int ntl = 0; ntl < 3; ++ntl)
        #pragma unroll
        for (int mt = 0; mt < 4; ++mt)
            acc[ntl][mt] = (f32x4)(0.0f);

    #pragma unroll
    for (int kc = 0; kc < 4; ++kc) {
        if (kc < 3) {
            #pragma unroll
            for (int ntl = 0; ntl < 3; ++ntl)
                bnxt[ntl] = *(const s16x8*)(bpb + (size_t)ntl * (16 * CH) + (kc + 1) * 32);
        }
        s16x8 a[4];
        #pragma unroll
        for (int mt = 0; mt < 4; ++mt) {
            int p  = mt * 16 + l15;
            int hs = (kc * 4 + lhi) ^ (p & 7);
            a[mt] = *(const s16x8*)(ldsA + p * 128 + hs * 8);   // ds_read_b128, conflict-free
        }
        #pragma unroll
        for (int ntl = 0; ntl < 3; ++ntl)
            #pragma unroll
            for (int mt = 0; mt < 4; ++mt)
                acc[ntl][mt] = __builtin_amdgcn_mfma_f32_16x16x32_bf16(a[mt], bcur[ntl], acc[ntl][mt], 0, 0, 0);
        #pragma unroll
        for (int ntl = 0; ntl < 3; ++ntl) bcur[ntl] = bnxt[ntl];
    }

    // ---- wave-private epilogue (no barriers; per-wave DS pipe is in-order) ----
    float (*myCT)[20] = ldsCT[w];     // [qc 48][dpj 16 pad 20]
    #pragma unroll
    for (int dpi = 0; dpi < 4; ++dpi) {
        int u = rr - dpi;                       // wave-uniform
        if ((unsigned)u < 21u) {
            // dump slice transposed: acc[ntl][dpi] = 4 consecutive dpj (lhi*4+reg) at qc=ntl*16+l15
            #pragma unroll
            for (int ntl = 0; ntl < 3; ++ntl)
                *(f32x4*)&myCT[ntl * 16 + l15][lhi * 4] = acc[ntl][dpi];
            // diagonal read (dpj=l15, qc=l15+v), store 16-contiguous j rows
            #pragma unroll
            for (int vb = 0; vb < 6; ++vb) {
                int v = vb * 4 + lhi;
                if (v < 21) {
                    float val = myCT[l15 + v][l15];
                    out[(((size_t)b * NUV + u * WIN + v) * HW + (i0 + dpi)) * HW + j0 + l15] = val;
                }
            }
        }
    }
}

extern "C" void kernel_launch(void* const* d_in, const int* in_sizes, int n_in,
                              void* d_out, int out_size, void* d_ws, size_t ws_size,
                              hipStream_t stream) {
    const float* x1 = (const float*)d_in[0];
    const float* x2 = (const float*)d_in[1];
    float* out = (float*)d_out;

    const size_t X1B_ELEMS = (size_t)BATCH * HW * HW * CH;          // 8,388,608
    const size_t X2B_ELEMS = (size_t)BATCH * PW * PWC * CH;         // 12,124,160
    if (ws_size < (X1B_ELEMS + X2B_ELEMS) * sizeof(unsigned short)) return;

    unsigned short* x1b = (unsigned short*)d_ws;
    unsigned short* x2b = x1b + X1B_ELEMS;

    hipMemsetAsync(x2b, 0, X2B_ELEMS * sizeof(unsigned short), stream);
    corr_transpose_kernel<<<16384, 256, 0, stream>>>(x1, x2, x1b, x2b);
    corr_mfma_kernel<<<3072, 512, 0, stream>>>(x1b, x2b, out);
}

// Round 4
// 65.886 us; speedup vs baseline: 1.8910x; 1.2218x over previous
//
#include <hip/hip_runtime.h>

#define BATCH 4
#define CH    128
#define HW    128
#define PAD   10
#define PW    148        // x2b rows (128 + 2*10)
#define PWC   160        // x2b row stride in cols (reads up to col 159 stay in-bounds)
#define WIN   21
#define NUV   441

typedef short s16x8 __attribute__((ext_vector_type(8)));
typedef float f32x4 __attribute__((ext_vector_type(4)));

static __device__ __forceinline__ unsigned short f32_to_bf16(float f) {
    unsigned int u = __float_as_uint(f);
    u += 0x7FFFu + ((u >> 16) & 1u);       // RNE
    return (unsigned short)(u >> 16);
}

// -------- transpose+convert: x[b][c][i][j] f32 -> channels-last bf16 --------
// blocks [0,8192): x1 -> x1b [4][128][128][128]
// blocks [8192,16384): x2 -> x2b [4][148][160][128] at +PAD offsets.
// NOTE: x2b borders are NEVER written (garbage) — the mfma epilogue masks
// out-of-image positions to 0.0 instead (each output uses exactly one x2 pos).
__global__ __launch_bounds__(256) void corr_transpose_kernel(
    const float* __restrict__ x1, const float* __restrict__ x2,
    unsigned short* __restrict__ x1b, unsigned short* __restrict__ x2b)
{
    __shared__ float lds[32][33];
    int bidx = blockIdx.x;
    int which = (bidx >= 8192) ? 1 : 0;
    if (which) bidx -= 8192;
    int tjt = bidx & 3;
    int tct = (bidx >> 2) & 3;
    int i   = (bidx >> 4) & 127;
    int b   = bidx >> 11;
    int c0 = tct * 32, j0 = tjt * 32;
    int t  = threadIdx.x;
    int tx = t & 31, ty = t >> 5;

    const float* __restrict__ src = which ? x2 : x1;
    #pragma unroll
    for (int k = 0; k < 4; ++k) {
        int c = c0 + ty + k * 8;
        lds[ty + k * 8][tx] = src[(((size_t)b * CH + c) * HW + i) * HW + j0 + tx];
    }
    __syncthreads();
    if (!which) {
        #pragma unroll
        for (int k = 0; k < 4; ++k) {
            int j = j0 + ty + k * 8;
            x1b[(((size_t)b * HW + i) * HW + j) * CH + c0 + tx] = f32_to_bf16(lds[tx][ty + k * 8]);
        }
    } else {
        #pragma unroll
        for (int k = 0; k < 4; ++k) {
            int j = j0 + ty + k * 8;
            x2b[(((size_t)b * PW + i + PAD) * PWC + (j + PAD)) * CH + c0 + tx] = f32_to_bf16(lds[tx][ty + k * 8]);
        }
    }
}

// -------- correlation GEMM, barrier-light --------
// grid: 3072 = 4 b x 32 ti x 8 tj x 3 z (XCD-swizzled). block: 512 thr = 8 waves.
// Pixel tile: 4x16 (M=64, mt == dpi). Each wave owns region row rr = z*8+w (48 q = 3 N-tiles).
// A tile staged once in LDS (global_load_lds, XOR-chunk swizzle); B direct global w/ prefetch.
// Epilogue: per-wave transposed C slice in LDS (b128 writes), diagonal read, masked
// coalesced stores (out-of-image x2 positions -> exact 0.0, replacing zero-padding).
__global__ __launch_bounds__(512, 4) void corr_mfma_kernel(
    const unsigned short* __restrict__ x1b,
    const unsigned short* __restrict__ x2b,
    float* __restrict__ out)
{
    __shared__ unsigned short ldsA[64 * 128];   // [pixel p][chunk-slot hs]*8shorts, 16 KB
    __shared__ float ldsCT[8][48][20];          // per-wave C slice, transposed [qc][dpj], 30 KB

    int bid  = blockIdx.x;
    int swz  = (bid & 7) * 384 + (bid >> 3);   // XCD-contiguous chunks
    int z    = swz % 3;
    int rest = swz / 3;                        // 0..1023
    int tj   = rest & 7;
    int ti   = (rest >> 3) & 31;
    int b    = rest >> 8;
    int i0 = ti * 4, j0 = tj * 16;

    int t    = threadIdx.x;
    int lane = t & 63;
    int w    = t >> 6;
    int l15  = lane & 15;
    int lhi  = lane >> 4;          // 0..3
    int rr   = z * 8 + w;          // owned region row, 0..23

    // ---- stage A tile: 64 px x 128 ch bf16 = 16 KB, 2 global_load_lds per wave ----
    #pragma unroll
    for (int it = 0; it < 2; ++it) {
        int s   = it * 8 + w;          // 0..15, 1 KB each
        int dpi = s >> 2;
        int k   = lane >> 4;           // 0..3
        int hs  = lane & 15;           // dest chunk slot
        int p   = s * 4 + k;
        int dpj = (s & 3) * 4 + k;
        int h   = hs ^ (p & 7);        // source chunk (pre-swizzled global src, linear LDS dest)
        const unsigned short* src =
            x1b + (((size_t)b * HW + i0 + dpi) * HW + j0 + dpj) * CH + h * 8;
        __builtin_amdgcn_global_load_lds(
            (const __attribute__((address_space(1))) void*)src,
            (__attribute__((address_space(3))) void*)(ldsA + s * 4 * 128),
            16, 0, 0);
    }

    // ---- B pointers + first-kc loads issued before the barrier (latency hides under it) ----
    const unsigned short* bpb =
        x2b + (((size_t)b * PW + i0 + rr) * PWC + j0 + l15) * CH + lhi * 8;

    s16x8 bcur[3], bnxt[3];
    #pragma unroll
    for (int ntl = 0; ntl < 3; ++ntl)
        bcur[ntl] = *(const s16x8*)(bpb + (size_t)ntl * (16 * CH));

    __syncthreads();   // A staged (vmcnt(0) drain covers global_load_lds)

    f32x4 acc[3][4];
    #pragma unroll
    for (int ntl = 0; ntl < 3; ++ntl)
        #pragma unroll
        for (int mt = 0; mt < 4; ++mt)
            acc[ntl][mt] = (f32x4)(0.0f);

    #pragma unroll
    for (int kc = 0; kc < 4; ++kc) {
        if (kc < 3) {
            #pragma unroll
            for (int ntl = 0; ntl < 3; ++ntl)
                bnxt[ntl] = *(const s16x8*)(bpb + (size_t)ntl * (16 * CH) + (kc + 1) * 32);
        }
        s16x8 a[4];
        #pragma unroll
        for (int mt = 0; mt < 4; ++mt) {
            int p  = mt * 16 + l15;
            int hs = (kc * 4 + lhi) ^ (p & 7);
            a[mt] = *(const s16x8*)(ldsA + p * 128 + hs * 8);   // ds_read_b128, conflict-free
        }
        #pragma unroll
        for (int ntl = 0; ntl < 3; ++ntl)
            #pragma unroll
            for (int mt = 0; mt < 4; ++mt)
                acc[ntl][mt] = __builtin_amdgcn_mfma_f32_16x16x32_bf16(a[mt], bcur[ntl], acc[ntl][mt], 0, 0, 0);
        #pragma unroll
        for (int ntl = 0; ntl < 3; ++ntl) bcur[ntl] = bnxt[ntl];
    }

    // ---- wave-private epilogue (no barriers; per-wave DS pipe is in-order) ----
    float (*myCT)[20] = ldsCT[w];     // [qc 48][dpj 16 pad 20]
    #pragma unroll
    for (int dpi = 0; dpi < 4; ++dpi) {
        int u = rr - dpi;                       // wave-uniform
        if ((unsigned)u < 21u) {
            int r2 = i0 + dpi + u - PAD;        // x2 image row (wave-uniform)
            // dump slice transposed: acc[ntl][dpi] = 4 consecutive dpj (lhi*4+reg) at qc=ntl*16+l15
            #pragma unroll
            for (int ntl = 0; ntl < 3; ++ntl)
                *(f32x4*)&myCT[ntl * 16 + l15][lhi * 4] = acc[ntl][dpi];
            // diagonal read (dpj=l15, qc=l15+v), store 16-contiguous j rows, masked
            #pragma unroll
            for (int vb = 0; vb < 6; ++vb) {
                int v = vb * 4 + lhi;
                if (v < 21) {
                    int c2 = j0 + l15 + v - PAD;    // x2 image col (per-lane)
                    float val = myCT[l15 + v][l15];
                    if ((unsigned)r2 >= 128u || (unsigned)c2 >= 128u) val = 0.0f;
                    out[(((size_t)b * NUV + u * WIN + v) * HW + (i0 + dpi)) * HW + j0 + l15] = val;
                }
            }
        }
    }
}

extern "C" void kernel_launch(void* const* d_in, const int* in_sizes, int n_in,
                              void* d_out, int out_size, void* d_ws, size_t ws_size,
                              hipStream_t stream) {
    const float* x1 = (const float*)d_in[0];
    const float* x2 = (const float*)d_in[1];
    float* out = (float*)d_out;

    const size_t X1B_ELEMS = (size_t)BATCH * HW * HW * CH;          // 8,388,608
    const size_t X2B_ELEMS = (size_t)BATCH * PW * PWC * CH;         // 12,124,160
    if (ws_size < (X1B_ELEMS + X2B_ELEMS) * sizeof(unsigned short)) return;

    unsigned short* x1b = (unsigned short*)d_ws;
    unsigned short* x2b = x1b + X1B_ELEMS;

    // No zero-fill: x2b pad region stays garbage; epilogue masks those outputs to 0.
    corr_transpose_kernel<<<16384, 256, 0, stream>>>(x1, x2, x1b, x2b);
    corr_mfma_kernel<<<3072, 512, 0, stream>>>(x1b, x2b, out);
}

// Round 5
// 61.716 us; speedup vs baseline: 2.0187x; 1.0676x over previous
//
#include <hip/hip_runtime.h>

#define BATCH 4
#define CH    128
#define HW    128
#define PAD   10
#define PW    148        // x2b rows (128 + 2*10)
#define PWC   160        // x2b row stride in cols (reads up to col 159 stay in-bounds)
#define WIN   21
#define NUV   441

typedef short s16x8 __attribute__((ext_vector_type(8)));
typedef float f32x4 __attribute__((ext_vector_type(4)));
typedef unsigned short u16x4 __attribute__((ext_vector_type(4)));

static __device__ __forceinline__ unsigned short f32_to_bf16(float f) {
    unsigned int u = __float_as_uint(f);
    u += 0x7FFFu + ((u >> 16) & 1u);       // RNE
    return (unsigned short)(u >> 16);
}

// -------- transpose+convert: x[b][c][i][j] f32 -> channels-last bf16 --------
// blocks [0,8192): x1 -> x1b [4][128][128][128]
// blocks [8192,16384): x2 -> x2b [4][148][160][128] at +PAD offsets.
// x2b borders are NEVER written (garbage); mfma epilogue masks those outputs to 0.
// Vectorized: float4 load -> f32 LDS (stride 34, b64-aligned) -> 4x b32 read,
// convert, one ushort4 (8 B) store per thread.
__global__ __launch_bounds__(256) void corr_transpose_kernel(
    const float* __restrict__ x1, const float* __restrict__ x2,
    unsigned short* __restrict__ x1b, unsigned short* __restrict__ x2b)
{
    __shared__ float lds[32][34];
    int bidx = blockIdx.x;
    int which = (bidx >= 8192) ? 1 : 0;
    if (which) bidx -= 8192;
    int tjt = bidx & 3;
    int tct = (bidx >> 2) & 3;
    int i   = (bidx >> 4) & 127;
    int b   = bidx >> 11;
    int c0 = tct * 32, j0 = tjt * 32;
    int t  = threadIdx.x;

    const float* __restrict__ src = which ? x2 : x1;

    // phase 1: 32 c-rows x 32 j, one float4 per thread (coalesced 128 B per c-row)
    int cl = t >> 3, jq = t & 7;
    float4 vv = *(const float4*)&src[(((size_t)b * CH + c0 + cl) * HW + i) * HW + j0 + jq * 4];
    lds[cl][jq * 4 + 0] = vv.x;
    lds[cl][jq * 4 + 1] = vv.y;
    lds[cl][jq * 4 + 2] = vv.z;
    lds[cl][jq * 4 + 3] = vv.w;
    __syncthreads();

    // phase 2: thread -> (j = t>>3, 4 c's), transposed read, ushort4 store
    int jl = t >> 3, cg = t & 7;
    u16x4 o;
    o[0] = f32_to_bf16(lds[cg * 4 + 0][jl]);
    o[1] = f32_to_bf16(lds[cg * 4 + 1][jl]);
    o[2] = f32_to_bf16(lds[cg * 4 + 2][jl]);
    o[3] = f32_to_bf16(lds[cg * 4 + 3][jl]);
    int j = j0 + jl, c = c0 + cg * 4;
    if (!which) {
        *(u16x4*)&x1b[(((size_t)b * HW + i) * HW + j) * CH + c] = o;
    } else {
        *(u16x4*)&x2b[(((size_t)b * PW + i + PAD) * PWC + (j + PAD)) * CH + c] = o;
    }
}

// -------- correlation GEMM, fully LDS-staged, single barrier --------
// grid: 6144 = 4 b x 32 ti x 8 tj x 6 z (XCD-swizzled). block: 256 thr = 4 waves.
// Pixel tile 4x16 (M=64, mt == dpi). Wave owns region row rr = z*4+w (48 q = 3 N-tiles).
// A tile (16 KB) + per-wave B row (12 KB, contiguous in x2b!) staged via
// global_load_lds dwordx4 with XOR-chunk swizzle; ONE __syncthreads; then pure
// ds_read_b128 + MFMA. Epilogue reuses the wave's own B region as CT scratch
// (wave-private, DS pipe in-order -> no barrier).
__global__ __launch_bounds__(256, 2) void corr_mfma_kernel(
    const unsigned short* __restrict__ x1b,
    const unsigned short* __restrict__ x2b,
    float* __restrict__ out)
{
    __shared__ unsigned short ldsA[64 * 128];       // 16 KB
    __shared__ unsigned short ldsB[4 * 48 * 128];   // 48 KB (4 waves x 12 KB)

    int bid  = blockIdx.x;
    int swz  = (bid & 7) * 768 + (bid >> 3);   // XCD-contiguous chunks (6144 % 8 == 0)
    int z    = swz % 6;
    int rest = swz / 6;                        // 0..1023
    int tj   = rest & 7;
    int ti   = (rest >> 3) & 31;
    int b    = rest >> 8;
    int i0 = ti * 4, j0 = tj * 16;

    int t    = threadIdx.x;
    int lane = t & 63;
    int w    = t >> 6;             // wave 0..3
    int l15  = lane & 15;
    int lhi  = lane >> 4;          // 0..3
    int rr   = z * 4 + w;          // owned region row, 0..23

    // ---- stage A tile: 64 px x 128 ch, 4 glds per wave (1 KB each) ----
    #pragma unroll
    for (int it = 0; it < 4; ++it) {
        int s   = w * 4 + it;          // 0..15
        int dpi = s >> 2;
        int pl  = lane >> 4;           // pixel within chunk-group
        int hs  = lane & 15;           // dest chunk slot
        int p   = s * 4 + pl;
        int dpj = (s & 3) * 4 + pl;
        int h   = hs ^ (p & 7);        // pre-swizzled global source chunk
        const unsigned short* srcp =
            x1b + (((size_t)b * HW + i0 + dpi) * HW + j0 + dpj) * CH + h * 8;
        __builtin_amdgcn_global_load_lds(
            (const __attribute__((address_space(1))) void*)srcp,
            (__attribute__((address_space(3))) void*)(ldsA + s * 512),
            16, 0, 0);
    }

    // ---- stage B row: 48 q x 128 ch contiguous, 12 glds per wave (1 KB each) ----
    const unsigned short* rowbase =
        x2b + (((size_t)b * PW + i0 + rr) * PWC + j0) * CH;
    unsigned short* myB = ldsB + w * (48 * 128);
    #pragma unroll
    for (int g = 0; g < 12; ++g) {
        int ql = lane >> 4;            // q within this 4-q group
        int hs = lane & 15;
        int q  = g * 4 + ql;
        int h  = hs ^ (q & 7);
        const unsigned short* srcp = rowbase + (size_t)q * CH + h * 8;
        __builtin_amdgcn_global_load_lds(
            (const __attribute__((address_space(1))) void*)srcp,
            (__attribute__((address_space(3))) void*)(myB + g * 512),
            16, 0, 0);
    }

    __syncthreads();   // drains all glds (vmcnt(0)); the only barrier

    f32x4 acc[3][4];
    #pragma unroll
    for (int ntl = 0; ntl < 3; ++ntl)
        #pragma unroll
        for (int mt = 0; mt < 4; ++mt)
            acc[ntl][mt] = (f32x4)(0.0f);

    #pragma unroll
    for (int kc = 0; kc < 4; ++kc) {
        int slotoff = ((kc * 4 + lhi) ^ (l15 & 7)) * 8;   // same for A and B (q%8 == l15%8)
        s16x8 a[4], bb[3];
        #pragma unroll
        for (int mt = 0; mt < 4; ++mt)
            a[mt] = *(const s16x8*)(ldsA + (mt * 16 + l15) * 128 + slotoff);
        #pragma unroll
        for (int ntl = 0; ntl < 3; ++ntl)
            bb[ntl] = *(const s16x8*)(myB + (ntl * 16 + l15) * 128 + slotoff);
        #pragma unroll
        for (int ntl = 0; ntl < 3; ++ntl)
            #pragma unroll
            for (int mt = 0; mt < 4; ++mt)
                acc[ntl][mt] = __builtin_amdgcn_mfma_f32_16x16x32_bf16(a[mt], bb[ntl], acc[ntl][mt], 0, 0, 0);
    }

    // ---- wave-private epilogue: CT scratch overlays this wave's B region ----
    float (*myCT)[20] = (float(*)[20])myB;    // 48 x 20 f32 = 3840 B < 12288 B
    #pragma unroll
    for (int dpi = 0; dpi < 4; ++dpi) {
        int u = rr - dpi;                       // wave-uniform
        if ((unsigned)u < 21u) {
            int r2 = i0 + dpi + u - PAD;        // x2 image row (wave-uniform)
            // dump slice transposed: 4 consecutive dpj (lhi*4+reg) at qc=ntl*16+l15
            #pragma unroll
            for (int ntl = 0; ntl < 3; ++ntl)
                *(f32x4*)&myCT[ntl * 16 + l15][lhi * 4] = acc[ntl][dpi];
            // diagonal read (dpj=l15, qc=l15+v), masked coalesced stores
            #pragma unroll
            for (int vb = 0; vb < 6; ++vb) {
                int v = vb * 4 + lhi;
                if (v < 21) {
                    int c2 = j0 + l15 + v - PAD;    // x2 image col (per-lane)
                    float val = myCT[l15 + v][l15];
                    if ((unsigned)r2 >= 128u || (unsigned)c2 >= 128u) val = 0.0f;
                    out[(((size_t)b * NUV + u * WIN + v) * HW + (i0 + dpi)) * HW + j0 + l15] = val;
                }
            }
        }
    }
}

extern "C" void kernel_launch(void* const* d_in, const int* in_sizes, int n_in,
                              void* d_out, int out_size, void* d_ws, size_t ws_size,
                              hipStream_t stream) {
    const float* x1 = (const float*)d_in[0];
    const float* x2 = (const float*)d_in[1];
    float* out = (float*)d_out;

    const size_t X1B_ELEMS = (size_t)BATCH * HW * HW * CH;          // 8,388,608
    const size_t X2B_ELEMS = (size_t)BATCH * PW * PWC * CH;         // 12,124,160
    if (ws_size < (X1B_ELEMS + X2B_ELEMS) * sizeof(unsigned short)) return;

    unsigned short* x1b = (unsigned short*)d_ws;
    unsigned short* x2b = x1b + X1B_ELEMS;

    // No zero-fill: x2b pad region stays garbage; epilogue masks those outputs to 0.
    corr_transpose_kernel<<<16384, 256, 0, stream>>>(x1, x2, x1b, x2b);
    corr_mfma_kernel<<<6144, 256, 0, stream>>>(x1b, x2b, out);
}

// Round 6
// 54.450 us; speedup vs baseline: 2.2881x; 1.1334x over previous
//
#include <hip/hip_runtime.h>

#define BATCH 4
#define CH    128
#define HW    128
#define PAD   10
#define PW    148        // x2b rows (128 + 2*10)
#define PWC   160        // x2b row stride in cols (reads up to col 159 stay in-bounds)
#define WIN   21
#define NUV   441
#define NQ    36         // staged B cols per wave (q = dpj + v <= 35)

typedef short s16x8 __attribute__((ext_vector_type(8)));
typedef float f32x4 __attribute__((ext_vector_type(4)));
typedef unsigned short u16x8 __attribute__((ext_vector_type(8)));

static __device__ __forceinline__ unsigned short f32_to_bf16(float f) {
    unsigned int u = __float_as_uint(f);
    u += 0x7FFFu + ((u >> 16) & 1u);       // RNE
    return (unsigned short)(u >> 16);
}

// -------- transpose+convert: x[b][c][i][j] f32 -> channels-last bf16 --------
// One block = ALL 128 channels of one (b, i, 32-wide j tile) -> phase-2 writes
// are full 256 B contiguous rows (no partial-line writes).
// blocks [0,2048): x1 -> x1b [4][128][128][128]
// blocks [2048,4096): x2 -> x2b [4][148][160][128] at +PAD offsets.
// x2b borders are NEVER written (garbage); mfma epilogue masks those outputs to 0.
__global__ __launch_bounds__(256) void corr_transpose_kernel(
    const float* __restrict__ x1, const float* __restrict__ x2,
    unsigned short* __restrict__ x1b, unsigned short* __restrict__ x2b)
{
    __shared__ float lds[128][33];       // 16.9 KB
    int bidx  = blockIdx.x;
    int which = bidx >= 2048;
    if (which) bidx -= 2048;
    int jt = bidx & 3;
    int i  = (bidx >> 2) & 127;
    int b  = bidx >> 9;
    int j0 = jt * 32;
    int t  = threadIdx.x;

    const float* __restrict__ src = which ? x2 : x1;

    // phase 1: 128 c-rows x 32 j, one float4 per thread per iter (coalesced 128 B/row)
    int cl = t >> 3, jq = t & 7;
    #pragma unroll
    for (int it = 0; it < 4; ++it) {
        int c = it * 32 + cl;
        float4 vv = *(const float4*)&src[(((size_t)b * CH + c) * HW + i) * HW + j0 + jq * 4];
        lds[c][jq * 4 + 0] = vv.x;
        lds[c][jq * 4 + 1] = vv.y;
        lds[c][jq * 4 + 2] = vv.z;
        lds[c][jq * 4 + 3] = vv.w;
    }
    __syncthreads();

    // phase 2: thread -> (j, 8 c's); 16 threads/j-row x 16 B = 256 B dense rows
    int jl = t >> 4, cg = t & 15;
    #pragma unroll
    for (int it = 0; it < 2; ++it) {
        int j = it * 16 + jl;
        u16x8 o;
        #pragma unroll
        for (int k = 0; k < 8; ++k) o[k] = f32_to_bf16(lds[cg * 8 + k][j]);
        if (!which)
            *(u16x8*)&x1b[(((size_t)b * HW + i) * HW + j0 + j) * CH + cg * 8] = o;
        else
            *(u16x8*)&x2b[(((size_t)b * PW + i + PAD) * PWC + (j0 + j + PAD)) * CH + cg * 8] = o;
    }
}

// -------- correlation GEMM, fully LDS-staged, single barrier --------
// grid: 6144 = 4 b x 32 ti x 8 tj x 6 z (XCD-swizzled). block: 256 thr = 4 waves.
// Pixel tile 4x16 (M=64, mt == dpi). Wave owns region row rr = z*4+w.
// B staged 36 q/wave (9 KB); MFMA N-tiles at q0 = {0,16,20} (overlap 20-31 dup,
// harmless) -> LDS 52 KB -> 3 blocks/CU (12 waves/CU vs 8 before).
// Epilogue reuses the wave's own B region as CT scratch (wave-private, DS in-order).
__global__ __launch_bounds__(256, 3) void corr_mfma_kernel(
    const unsigned short* __restrict__ x1b,
    const unsigned short* __restrict__ x2b,
    float* __restrict__ out)
{
    __shared__ unsigned short ldsA[64 * 128];       // 16 KB
    __shared__ unsigned short ldsB[4 * NQ * 128];   // 36 KB (4 waves x 9 KB)

    int bid  = blockIdx.x;
    int swz  = (bid & 7) * 768 + (bid >> 3);   // XCD-contiguous chunks (6144 % 8 == 0)
    int z    = swz % 6;
    int rest = swz / 6;                        // 0..1023
    int tj   = rest & 7;
    int ti   = (rest >> 3) & 31;
    int b    = rest >> 8;
    int i0 = ti * 4, j0 = tj * 16;

    int t    = threadIdx.x;
    int lane = t & 63;
    int w    = t >> 6;             // wave 0..3
    int l15  = lane & 15;
    int lhi  = lane >> 4;          // 0..3
    int rr   = z * 4 + w;          // owned region row, 0..23

    // ---- stage A tile: 64 px x 128 ch, 4 glds per wave (1 KB each) ----
    #pragma unroll
    for (int it = 0; it < 4; ++it) {
        int s   = w * 4 + it;          // 0..15
        int dpi = s >> 2;
        int pl  = lane >> 4;
        int hs  = lane & 15;           // dest chunk slot
        int p   = s * 4 + pl;
        int dpj = (s & 3) * 4 + pl;
        int h   = hs ^ (p & 7);        // pre-swizzled global source chunk
        const unsigned short* srcp =
            x1b + (((size_t)b * HW + i0 + dpi) * HW + j0 + dpj) * CH + h * 8;
        __builtin_amdgcn_global_load_lds(
            (const __attribute__((address_space(1))) void*)srcp,
            (__attribute__((address_space(3))) void*)(ldsA + s * 512),
            16, 0, 0);
    }

    // ---- stage B row: 36 q x 128 ch contiguous, 9 glds per wave ----
    const unsigned short* rowbase =
        x2b + (((size_t)b * PW + i0 + rr) * PWC + j0) * CH;
    unsigned short* myB = ldsB + w * (NQ * 128);
    #pragma unroll
    for (int g = 0; g < 9; ++g) {
        int ql = lane >> 4;
        int hs = lane & 15;
        int q  = g * 4 + ql;
        int h  = hs ^ (q & 7);
        const unsigned short* srcp = rowbase + (size_t)q * CH + h * 8;
        __builtin_amdgcn_global_load_lds(
            (const __attribute__((address_space(1))) void*)srcp,
            (__attribute__((address_space(3))) void*)(myB + g * 512),
            16, 0, 0);
    }

    __syncthreads();   // drains all glds (vmcnt(0)); the only barrier

    f32x4 acc[3][4];
    #pragma unroll
    for (int ntl = 0; ntl < 3; ++ntl)
        #pragma unroll
        for (int mt = 0; mt < 4; ++mt)
            acc[ntl][mt] = (f32x4)(0.0f);

    const int q0tab[3] = {0, 16, 20};

    #pragma unroll
    for (int kc = 0; kc < 4; ++kc) {
        s16x8 a[4], bb[3];
        #pragma unroll
        for (int mt = 0; mt < 4; ++mt) {
            int slot = (kc * 4 + lhi) ^ (l15 & 7);
            a[mt] = *(const s16x8*)(ldsA + (mt * 16 + l15) * 128 + slot * 8);
        }
        #pragma unroll
        for (int ntl = 0; ntl < 3; ++ntl) {
            int q    = q0tab[ntl] + l15;
            int slot = (kc * 4 + lhi) ^ (q & 7);
            bb[ntl] = *(const s16x8*)(myB + q * 128 + slot * 8);
        }
        __builtin_amdgcn_s_setprio(1);
        #pragma unroll
        for (int ntl = 0; ntl < 3; ++ntl)
            #pragma unroll
            for (int mt = 0; mt < 4; ++mt)
                acc[ntl][mt] = __builtin_amdgcn_mfma_f32_16x16x32_bf16(a[mt], bb[ntl], acc[ntl][mt], 0, 0, 0);
        __builtin_amdgcn_s_setprio(0);
    }

    // ---- wave-private epilogue: CT scratch overlays this wave's B region ----
    float (*myCT)[20] = (float(*)[20])myB;    // 36 x 20 f32 = 2880 B < 9216 B
    #pragma unroll
    for (int dpi = 0; dpi < 4; ++dpi) {
        int u = rr - dpi;                       // wave-uniform
        if ((unsigned)u < 21u) {
            int r2 = i0 + dpi + u - PAD;        // x2 image row (wave-uniform)
            // dump slice transposed: 4 consecutive dpj (lhi*4+reg) at qc = q0+l15
            #pragma unroll
            for (int ntl = 0; ntl < 3; ++ntl)
                *(f32x4*)&myCT[q0tab[ntl] + l15][lhi * 4] = acc[ntl][dpi];
            // diagonal read (dpj=l15, qc=l15+v), masked coalesced stores
            #pragma unroll
            for (int vb = 0; vb < 6; ++vb) {
                int v = vb * 4 + lhi;
                if (v < 21) {
                    int c2 = j0 + l15 + v - PAD;    // x2 image col (per-lane)
                    float val = myCT[l15 + v][l15];
                    if ((unsigned)r2 >= 128u || (unsigned)c2 >= 128u) val = 0.0f;
                    out[(((size_t)b * NUV + u * WIN + v) * HW + (i0 + dpi)) * HW + j0 + l15] = val;
                }
            }
        }
    }
}

extern "C" void kernel_launch(void* const* d_in, const int* in_sizes, int n_in,
                              void* d_out, int out_size, void* d_ws, size_t ws_size,
                              hipStream_t stream) {
    const float* x1 = (const float*)d_in[0];
    const float* x2 = (const float*)d_in[1];
    float* out = (float*)d_out;

    const size_t X1B_ELEMS = (size_t)BATCH * HW * HW * CH;          // 8,388,608
    const size_t X2B_ELEMS = (size_t)BATCH * PW * PWC * CH;         // 12,124,160
    if (ws_size < (X1B_ELEMS + X2B_ELEMS) * sizeof(unsigned short)) return;

    unsigned short* x1b = (unsigned short*)d_ws;
    unsigned short* x2b = x1b + X1B_ELEMS;

    // No zero-fill: x2b pad region stays garbage; epilogue masks those outputs to 0.
    corr_transpose_kernel<<<4096, 256, 0, stream>>>(x1, x2, x1b, x2b);
    corr_mfma_kernel<<<6144, 256, 0, stream>>>(x1b, x2b, out);
}